// Round 8
// baseline (100.150 us; speedup 1.0000x reference)
//
#include <hip/hip_runtime.h>

// SampledSoftmaxLoss: N=51200 rows, D=64, K=100 negatives, V=100001 items.
// loss = sum_n w_n * (logsumexp(logits_n) - pos_logit_n) / sum_n w_n
// logits = cos_sim(vo_n, item_idx) / 0.05
//
// r14: INT8 SDOT4 + TWO-PASS D-SPLIT. Ledger:
//  r5   59.7us fp8 single table: FETCH 152MB @2.6TB/s.
//  r9/r12: D-split -> table gathers become cache hits (FETCH = streams
//       only). Capacity theory CONFIRMED; those rounds lost on structure.
//  r13  58.0us int8 sdot4 single pass: VALU 13.9% (!), FETCH 140MB
//       @2.49TB/s -> pure HBM random-64B-line wall. Structure is now free;
//       only the miss traffic remains.
// This round: r13's lane-owns-slot sdot4 structure x r12's kernel-boundary
// D-split. Pass A: tabA (dims 0-31, 32B/row, 3.2MB < 4MB L2/XCD) ->
// 32-dim dots; d0,d1 are EXACT int16 (|d|<=~131^2), packed one dword/lane,
// NT-stored to part[N][64] (13.1MB stream). Pass B: tabB resident,
// complete dots + softmax + loss. Numerics identical to r13 (exact
// partials). No barriers anywhere in main loops; NT on all streams so
// they don't evict the resident half-table.

#define D_DIM 64
#define K_NEG 100
#define INV_TEMP 20.0f
#define MAX_LOGIT 20.0f
#define LOG2E 1.4426950408889634f
#define LN2 0.6931471805599453f
#define MAXL2 28.853900817779268f        // MAX_LOGIT * LOG2E
#define MCONST (INV_TEMP / (127.0f * 127.0f))   // logit = dot_int * MCONST
#define MC2 (MCONST * LOG2E)

#define NBLK_MAIN 2048
#define NBLK_QNT 1024

typedef float fv4 __attribute__((ext_vector_type(4)));
typedef unsigned int uv4 __attribute__((ext_vector_type(4)));

__device__ __forceinline__ int DOT4(int a, int b, int c) {
#if __has_builtin(__builtin_amdgcn_sdot4)
  return __builtin_amdgcn_sdot4(a, b, c, false);
#else
  int r = c;
#pragma unroll
  for (int i = 0; i < 4; ++i)
    r += (int)(signed char)(a >> (8 * i)) * (int)(signed char)(b >> (8 * i));
  return r;
#endif
}

__device__ __forceinline__ unsigned int pack8(const fv4 x, float s) {
  const int b0 = (int)rintf(x.x * s) & 255;
  const int b1 = (int)rintf(x.y * s) & 255;
  const int b2 = (int)rintf(x.z * s) & 255;
  const int b3 = (int)rintf(x.w * s) & 255;
  return (unsigned)b0 | ((unsigned)b1 << 8) | ((unsigned)b2 << 16) |
         ((unsigned)b3 << 24);
}

// ---- Pass 1: l2-normalize + int8-quantize items (D-split) AND queries ----
// wave handles 4 rows x 16 lanes x 4 dims; one packed dword per lane.
__global__ __launch_bounds__(256) void quantize_kernel(
    const float* __restrict__ items, unsigned int* __restrict__ tabA,
    unsigned int* __restrict__ tabB, int V,
    const float* __restrict__ oe, unsigned int* __restrict__ q8, int N) {
  const int lane = threadIdx.x & 63;
  const int wid  = threadIdx.x >> 6;
  const int g = lane >> 4, q = lane & 15;
  const int waveId = blockIdx.x * 4 + wid;
  const int nWaves = gridDim.x * 4;
  for (int base = waveId * 4; base < V; base += nWaves * 4) {
    const int r = base + g;
    const bool act = (r < V);
    fv4 x = {0.f, 0.f, 0.f, 0.f};
    if (act) x = *reinterpret_cast<const fv4*>(items + (size_t)r * D_DIM + q * 4);
    float ss = x.x * x.x + x.y * x.y + x.z * x.z + x.w * x.w;
    ss += __shfl_xor(ss, 1);
    ss += __shfl_xor(ss, 2);
    ss += __shfl_xor(ss, 4);
    ss += __shfl_xor(ss, 8);
    const float s = 127.0f / fmaxf(sqrtf(ss), 1e-12f);
    if (act) {
      const unsigned int u = pack8(x, s);
      if (q < 8) tabA[(size_t)r * 8 + q] = u;
      else       tabB[(size_t)r * 8 + (q - 8)] = u;
    }
  }
  for (int base = waveId * 4; base < N; base += nWaves * 4) {
    const int r = base + g;
    const bool act = (r < N);
    fv4 x = {0.f, 0.f, 0.f, 0.f};
    if (act) x = *reinterpret_cast<const fv4*>(oe + (size_t)r * D_DIM + q * 4);
    float ss = x.x * x.x + x.y * x.y + x.z * x.z + x.w * x.w;
    ss += __shfl_xor(ss, 1);
    ss += __shfl_xor(ss, 2);
    ss += __shfl_xor(ss, 4);
    ss += __shfl_xor(ss, 8);
    const float s = 127.0f / fmaxf(sqrtf(ss), 1e-12f);
    if (act) q8[(size_t)r * 16 + q] = pack8(x, s);   // dwords 0-7=A, 8-15=B
  }
}

// ---- Pass 2a: 32-dim partial dots vs tabA (L2-resident), exact int16 ----
// One wave per row; lane owns slot lane (0=pos) and slot 64+lane (<=100).
__global__ __launch_bounds__(256) void partA_kernel(
    const unsigned int* __restrict__ q8,   // [N][16] dwords int8
    const int*   __restrict__ tgt,         // [N]
    const unsigned int* __restrict__ tabA, // [V][8] dwords int8 (dims 0-31)
    const int*   __restrict__ negi,        // [N,100]
    const int*   __restrict__ alti,        // [N,100]
    unsigned int* __restrict__ part,       // [N][64] packed int16 pairs
    int N) {
  const int lane = threadIdx.x & 63;
  const int waveId = blockIdx.x * 4 + (threadIdx.x >> 6);
  const int nWaves = gridDim.x * 4;
  const bool v1ok = (lane <= K_NEG - 64);  // slot1 = 64+lane valid

  int row = waveId;
  int t_r = 0, n0 = 0, n1 = 0;
  if (row < N) {
    t_r = tgt[row];
    const int* nr = negi + (size_t)row * K_NEG;
    if (lane >= 1) n0 = nr[lane - 1];
    if (v1ok) n1 = nr[63 + lane];
  }

  while (row < N) {
    const int nxt = row + nWaves;

    // resolve collisions (alt loaded only on rare collision, execz-skipped)
    const int* ar = alti + (size_t)row * K_NEG;
    int i0 = (lane == 0) ? t_r : n0;
    if (lane >= 1 && i0 == t_r) i0 = ar[lane - 1];
    int i1 = v1ok ? n1 : 0;
    if (v1ok && i1 == t_r) i1 = ar[63 + lane];

    // gathers: two 32B half-rows + 32B query half (dims 0-31)
    const uv4* t0 = reinterpret_cast<const uv4*>(tabA + ((size_t)(unsigned)i0 << 3));
    const uv4* t1 = reinterpret_cast<const uv4*>(tabA + ((size_t)(unsigned)i1 << 3));
    const uv4 a0 = t0[0], a1 = t0[1];
    const uv4 b0 = t1[0], b1 = t1[1];
    const uv4* qp = reinterpret_cast<const uv4*>(q8 + (size_t)row * 16);
    const uv4 q0 = qp[0], q1 = qp[1];

    // prefetch next row's index streams under the gather latency
    int p_t = 0, pn0 = 0, pn1 = 0;
    if (nxt < N) {
      p_t = tgt[nxt];
      const int* nr = negi + (size_t)nxt * K_NEG;
      if (lane >= 1) pn0 = __builtin_nontemporal_load(nr + lane - 1);
      if (v1ok) pn1 = __builtin_nontemporal_load(nr + 63 + lane);
    }

    // two 32-dim int8 dots in-lane (8 sdot4 each, independent chains)
    int d0 = 0, d1 = 0;
    d0 = DOT4((int)a0.x, (int)q0.x, d0);
    d1 = DOT4((int)b0.x, (int)q0.x, d1);
    d0 = DOT4((int)a0.y, (int)q0.y, d0);
    d1 = DOT4((int)b0.y, (int)q0.y, d1);
    d0 = DOT4((int)a0.z, (int)q0.z, d0);
    d1 = DOT4((int)b0.z, (int)q0.z, d1);
    d0 = DOT4((int)a0.w, (int)q0.w, d0);
    d1 = DOT4((int)b0.w, (int)q0.w, d1);
    d0 = DOT4((int)a1.x, (int)q1.x, d0);
    d1 = DOT4((int)b1.x, (int)q1.x, d1);
    d0 = DOT4((int)a1.y, (int)q1.y, d0);
    d1 = DOT4((int)b1.y, (int)q1.y, d1);
    d0 = DOT4((int)a1.z, (int)q1.z, d0);
    d1 = DOT4((int)b1.z, (int)q1.z, d1);
    d0 = DOT4((int)a1.w, (int)q1.w, d0);
    d1 = DOT4((int)b1.w, (int)q1.w, d1);

    // pack exact int16 partials -> one coalesced dword per lane
    const unsigned int pu = ((unsigned)(unsigned short)(short)d0) |
                            (((unsigned)(unsigned short)(short)d1) << 16);
    __builtin_nontemporal_store(pu, part + (size_t)row * 64 + lane);

    t_r = p_t; n0 = pn0; n1 = pn1;
    row = nxt;
  }
}

// ---- Pass 2b: complete dots vs tabB (L2-resident) + softmax + loss ----
__global__ __launch_bounds__(256) void loss_kernel(
    const unsigned int* __restrict__ q8,   // [N][16] dwords int8
    const int*   __restrict__ tgt,         // [N]
    const unsigned int* __restrict__ tabB, // [V][8] dwords int8 (dims 32-63)
    const float* __restrict__ wgt,         // [N]
    const int*   __restrict__ negi,        // [N,100]
    const int*   __restrict__ alti,        // [N,100]
    const unsigned int* __restrict__ part, // [N][64] packed int16 pairs
    float2*      __restrict__ partials,    // [gridDim.x]
    int N) {
  __shared__ float2 s_red[4];
  const int lane = threadIdx.x & 63;
  const int wid  = threadIdx.x >> 6;
  const int waveId = blockIdx.x * 4 + wid;
  const int nWaves = gridDim.x * 4;
  const bool v1ok = (lane <= K_NEG - 64);

  float num = 0.f, den = 0.f;

  int row = waveId;
  int t_r = 0, n0 = 0, n1 = 0;
  float w = 0.f;
  if (row < N) {
    t_r = tgt[row];
    w = wgt[row];
    const int* nr = negi + (size_t)row * K_NEG;
    if (lane >= 1) n0 = nr[lane - 1];
    if (v1ok) n1 = nr[63 + lane];
  }

  while (row < N) {
    const int nxt = row + nWaves;

    const int* ar = alti + (size_t)row * K_NEG;
    int i0 = (lane == 0) ? t_r : n0;
    if (lane >= 1 && i0 == t_r) i0 = ar[lane - 1];
    int i1 = v1ok ? n1 : 0;
    if (v1ok && i1 == t_r) i1 = ar[63 + lane];

    // gathers: two 32B half-rows (dims 32-63) + query half + partials
    const uv4* t0 = reinterpret_cast<const uv4*>(tabB + ((size_t)(unsigned)i0 << 3));
    const uv4* t1 = reinterpret_cast<const uv4*>(tabB + ((size_t)(unsigned)i1 << 3));
    const uv4 a0 = t0[0], a1 = t0[1];
    const uv4 b0 = t1[0], b1 = t1[1];
    const uv4* qp = reinterpret_cast<const uv4*>(q8 + (size_t)row * 16);
    const uv4 q0 = qp[2], q1 = qp[3];
    const unsigned int pu =
        __builtin_nontemporal_load(part + (size_t)row * 64 + lane);

    int p_t = 0, pn0 = 0, pn1 = 0;
    float p_w = 0.f;
    if (nxt < N) {
      p_t = tgt[nxt];
      p_w = wgt[nxt];
      const int* nr = negi + (size_t)nxt * K_NEG;
      if (lane >= 1) pn0 = __builtin_nontemporal_load(nr + lane - 1);
      if (v1ok) pn1 = __builtin_nontemporal_load(nr + 63 + lane);
    }

    int d0 = (int)(short)(pu & 0xffffu);       // exact A-half partials
    int d1 = (int)(short)(pu >> 16);
    d0 = DOT4((int)a0.x, (int)q0.x, d0);
    d1 = DOT4((int)b0.x, (int)q0.x, d1);
    d0 = DOT4((int)a0.y, (int)q0.y, d0);
    d1 = DOT4((int)b0.y, (int)q0.y, d1);
    d0 = DOT4((int)a0.z, (int)q0.z, d0);
    d1 = DOT4((int)b0.z, (int)q0.z, d1);
    d0 = DOT4((int)a0.w, (int)q0.w, d0);
    d1 = DOT4((int)b0.w, (int)q0.w, d1);
    d0 = DOT4((int)a1.x, (int)q1.x, d0);
    d1 = DOT4((int)b1.x, (int)q1.x, d1);
    d0 = DOT4((int)a1.y, (int)q1.y, d0);
    d1 = DOT4((int)b1.y, (int)q1.y, d1);
    d0 = DOT4((int)a1.z, (int)q1.z, d0);
    d1 = DOT4((int)b1.z, (int)q1.z, d1);
    d0 = DOT4((int)a1.w, (int)q1.w, d0);
    d1 = DOT4((int)b1.w, (int)q1.w, d1);

    float e = exp2f(fmaf((float)d0, MC2, -MAXL2));
    if (v1ok) e += exp2f(fmaf((float)d1, MC2, -MAXL2));

    e += __shfl_xor(e, 1);
    e += __shfl_xor(e, 2);
    e += __shfl_xor(e, 4);
    e += __shfl_xor(e, 8);
    e += __shfl_xor(e, 16);
    e += __shfl_xor(e, 32);
    if (lane == 0) {
      const float pos = (float)d0 * MCONST;    // lane0 slot0 = positive
      const float lse = log2f(e) * LN2 + MAX_LOGIT;
      const float loss = lse - pos;
      if (w > 0.f) {
        num += loss * w;
        den += w;
      }
    }

    t_r = p_t; n0 = pn0; n1 = pn1; w = p_w;
    row = nxt;
  }

  if (lane == 0) s_red[wid] = make_float2(num, den);
  __syncthreads();
  if (threadIdx.x == 0) {
    float n = 0.f, d = 0.f;
#pragma unroll
    for (int i = 0; i < 4; ++i) { n += s_red[i].x; d += s_red[i].y; }
    partials[blockIdx.x] = make_float2(n, d);
  }
}

// ---------------- Pass 3: final reduce ----------------
__global__ __launch_bounds__(256) void finish_kernel(
    const float2* __restrict__ partials, int nblk, float* __restrict__ out) {
  float num = 0.f, den = 0.f;
  for (int i = threadIdx.x; i < nblk; i += 256) {
    const float2 p = partials[i];
    num += p.x;
    den += p.y;
  }
#pragma unroll
  for (int m = 1; m < 64; m <<= 1) {
    num += __shfl_xor(num, m);
    den += __shfl_xor(den, m);
  }
  __shared__ float2 red[4];
  const int wid = threadIdx.x >> 6;
  const int lane = threadIdx.x & 63;
  if (lane == 0) red[wid] = make_float2(num, den);
  __syncthreads();
  if (threadIdx.x == 0) {
    float n = 0.f, d = 0.f;
#pragma unroll
    for (int i = 0; i < 4; ++i) { n += red[i].x; d += red[i].y; }
    out[0] = n / d;
  }
}

extern "C" void kernel_launch(void* const* d_in, const int* in_sizes, int n_in,
                              void* d_out, int out_size, void* d_ws, size_t ws_size,
                              hipStream_t stream) {
  const float* oe    = (const float*)d_in[0];  // output_embeddings [B,S,64]
  const int*   tgt   = (const int*)  d_in[1];  // target_ids [B,S]
  const float* items = (const float*)d_in[2];  // all_item_embeddings [V,64]
  const float* wgt   = (const float*)d_in[3];  // supervision_weights [B,S]
  const int*   negi  = (const int*)  d_in[4];  // neg_indices [N,100]
  const int*   alti  = (const int*)  d_in[5];  // alt_neg_indices [N,100]

  const int N = in_sizes[0] / D_DIM;  // 51200
  const int V = in_sizes[2] / D_DIM;  // 100001

  unsigned int* tabA = (unsigned int*)d_ws;          // V*32 B (dims 0-31)
  unsigned int* tabB = tabA + (size_t)V * 8;         // V*32 B (dims 32-63)
  size_t off = ((size_t)V * 64 + 255) & ~(size_t)255;
  unsigned int* q8 = (unsigned int*)((char*)d_ws + off);   // N*64 B queries
  size_t off2 = (off + (size_t)N * 64 + 255) & ~(size_t)255;
  unsigned int* part = (unsigned int*)((char*)d_ws + off2); // N*256 B partials
  size_t off3 = (off2 + (size_t)N * 256 + 255) & ~(size_t)255;
  float2* partials = (float2*)((char*)d_ws + off3);

  quantize_kernel<<<NBLK_QNT, 256, 0, stream>>>(items, tabA, tabB, V, oe, q8, N);
  partA_kernel<<<NBLK_MAIN, 256, 0, stream>>>(q8, tgt, tabA, negi, alti,
                                              part, N);
  loss_kernel<<<NBLK_MAIN, 256, 0, stream>>>(q8, tgt, tabB, wgt, negi, alti,
                                             part, partials, N);
  finish_kernel<<<1, 256, 0, stream>>>(partials, NBLK_MAIN, (float*)d_out);
}